// Round 2
// baseline (6635.208 us; speedup 1.0000x reference)
//
#include <hip/hip_runtime.h>
#include <hip/hip_bf16.h>

typedef float f32x4 __attribute__((ext_vector_type(4)));

#define EMB   300
#define HID   300
#define G4    1200
#define TAGS  64
#define BB    64
#define TT    512
#define MM    (BB*TT)

__device__ __forceinline__ float sigm(float x) {
    return 1.0f / (1.0f + __expf(-x));
}
__device__ __forceinline__ float tanh_fast(float x) {
    float e = __expf(-2.0f * fabsf(x));
    float r = (1.0f - e) / (1.0f + e);
    return copysignf(r, x);
}
__device__ __forceinline__ unsigned short f2bf(float f) {
    unsigned int u = __float_as_uint(f);
    unsigned int r = (u + 0x7FFFu + ((u >> 16) & 1u)) >> 16;   // RNE
    return (unsigned short)r;
}
__device__ __forceinline__ float bf2f(unsigned short s) {
    return __uint_as_float(((unsigned int)s) << 16);
}

// ---------------- K1: xg = emb[tokens] @ W + bias, stored bf16 --------------
// grid (512, 19, 2), block 256. Tile 64x64, K-chunk 20, 4x4 micro-tile.
__global__ __launch_bounds__(256)
void k1_xg(const int* __restrict__ tokens, const int* __restrict__ seqlen,
           const float* __restrict__ emb,
           const float* __restrict__ Wf, const float* __restrict__ bf,
           const float* __restrict__ Wb, const float* __restrict__ bb,
           unsigned short* __restrict__ xgf, unsigned short* __restrict__ xgb)
{
    const int z = blockIdx.z;
    const float* __restrict__ W    = z ? Wb : Wf;
    const float* __restrict__ bias = z ? bb : bf;
    unsigned short* __restrict__ out = z ? xgb : xgf;

    const int row0 = blockIdx.x * 64;
    const int b    = row0 >> 9;
    const int t0   = row0 & 511;
    if (t0 >= seqlen[b]) return;       // whole strip masked -> xg never used

    const int n0 = blockIdx.y * 64;

    __shared__ __align__(16) float As[20][64];
    __shared__ __align__(16) float Bs[20][64];
    __shared__ int toks[64];

    const int tid = threadIdx.x;
    if (tid < 64) toks[tid] = tokens[row0 + tid];
    __syncthreads();

    const int tx = tid & 15, ty = tid >> 4;
    const int rm = ty * 4,   cn = tx * 4;

    float acc[4][4] = {{0.f}};

    const int ar  = tid & 63;
    const int ak0 = (tid >> 6) * 5;

    for (int kc = 0; kc < EMB; kc += 20) {
        const float* arow = emb + (size_t)toks[ar] * EMB + (kc + ak0);
        #pragma unroll
        for (int u = 0; u < 5; ++u) As[ak0 + u][ar] = arow[u];
        const int colb = n0 + ar;
        #pragma unroll
        for (int u = 0; u < 5; ++u) {
            float v = 0.f;
            if (colb < G4) v = W[(size_t)(kc + ak0 + u) * G4 + colb];
            Bs[ak0 + u][ar] = v;
        }
        __syncthreads();
        #pragma unroll
        for (int k = 0; k < 20; ++k) {
            f32x4 av = *(const f32x4*)&As[k][rm];
            f32x4 bv = *(const f32x4*)&Bs[k][cn];
            #pragma unroll
            for (int i = 0; i < 4; ++i)
                #pragma unroll
                for (int j = 0; j < 4; ++j)
                    acc[i][j] = fmaf(av[i], bv[j], acc[i][j]);
        }
        __syncthreads();
    }
    #pragma unroll
    for (int i = 0; i < 4; ++i) {
        const int row = row0 + rm + i;
        #pragma unroll
        for (int j = 0; j < 4; ++j) {
            const int col = n0 + cn + j;
            if (col < G4)
                out[(size_t)row * G4 + col] = f2bf(acc[i][j] + bias[col]);
        }
    }
}

// ---------------- K2: LSTM scans + fused FC projection ----------------------
// 64 blocks = 32 batch-pairs x 2 dirs, 448 threads.
//   tid 0..299   : gate dot (4 cols each), U streamed from L2, shared across
//                  the 2 batches; also gate nonlinearity phase (j = tid).
//   tid 320..447 : project PREVIOUS step's h (in LDS) through Wfc half (LDS),
//                  overlapped with the dot phase.
// fwd blocks write out = bfc + h @ Wfc[0:300]; bwd blocks write bwdp
// (separate buffer, no race); k3 adds.
__global__ __launch_bounds__(448)
void k2_rnn(const int* __restrict__ seqlen,
            const float* __restrict__ Uf, const float* __restrict__ Ub,
            const unsigned short* __restrict__ xgf,
            const unsigned short* __restrict__ xgb,
            const float* __restrict__ Wfc, const float* __restrict__ bfc,
            float* __restrict__ outbuf, float* __restrict__ bwdp)
{
    const int w    = blockIdx.x;
    const int dir  = w & 1;
    const int pair = w >> 1;
    const int bA   = pair * 2, bBt = pair * 2 + 1;
    const int LA   = seqlen[bA], LB = seqlen[bBt];
    const int maxL = LA > LB ? LA : LB;
    const float* __restrict__ U = dir ? Ub : Uf;
    const unsigned short* __restrict__ xg = dir ? xgb : xgf;
    float* __restrict__ dst = dir ? bwdp : outbuf;

    __shared__ __align__(16) float hA[HID], hB[HID];
    __shared__ __align__(16) float gA[G4], gB[G4];
    __shared__ __align__(16) float W2s[HID][TAGS];   // 76.8 KB

    const int tid = threadIdx.x;
    for (int i = tid; i < HID * TAGS; i += 448)
        W2s[i >> 6][i & 63] = Wfc[(size_t)dir * HID * TAGS + i];
    for (int i = tid; i < HID; i += 448) { hA[i] = 0.f; hB[i] = 0.f; }
    __syncthreads();

    float cAr = 0.f, cBr = 0.f;
    const int c0 = tid * 4;

    // projection thread identity
    const int p    = tid - 320;
    const int bsel = p >> 6;
    const int col  = p & 63;
    const float* hs  = (p >= 0 && bsel) ? hB : hA;
    const int   bprj = bsel ? bBt : bA;

    for (int ti = 0; ti < maxL; ++ti) {
        const int tf = dir ? (maxL - 1 - ti) : ti;
        if (tid < 300) {
            const unsigned short* xrA = xg + ((size_t)bA  * TT + tf) * G4 + c0;
            const unsigned short* xrB = xg + ((size_t)bBt * TT + tf) * G4 + c0;
            ushort4 ua = *(const ushort4*)xrA;
            ushort4 ub = *(const ushort4*)xrB;
            f32x4 accA = { bf2f(ua.x), bf2f(ua.y), bf2f(ua.z), bf2f(ua.w) };
            f32x4 accB = { bf2f(ub.x), bf2f(ub.y), bf2f(ub.z), bf2f(ub.w) };
            const float* Up = U + c0;
            for (int k = 0; k < HID; k += 4) {
                f32x4 ha = *(const f32x4*)&hA[k];
                f32x4 hb = *(const f32x4*)&hB[k];
                #pragma unroll
                for (int kk = 0; kk < 4; ++kk) {
                    f32x4 u = *(const f32x4*)(Up + (size_t)(k + kk) * G4);
                    accA += ha[kk] * u;
                    accB += hb[kk] * u;
                }
            }
            *(f32x4*)&gA[c0] = accA;
            *(f32x4*)&gB[c0] = accB;
        } else if (tid >= 320 && ti > 0) {
            // project h of previous step (still in LDS)
            float acc = dir ? 0.f : bfc[col];
            for (int j = 0; j < HID; j += 4) {
                f32x4 h4 = *(const f32x4*)&hs[j];
                acc = fmaf(h4.x, W2s[j + 0][col], acc);
                acc = fmaf(h4.y, W2s[j + 1][col], acc);
                acc = fmaf(h4.z, W2s[j + 2][col], acc);
                acc = fmaf(h4.w, W2s[j + 3][col], acc);
            }
            const int rowp = dir ? (tf + 1) : (tf - 1);
            __builtin_nontemporal_store(acc,
                dst + ((size_t)bprj * TT + rowp) * TAGS + col);
        }
        __syncthreads();
        if (tid < 300) {
            const int j = tid;
            {
                float i_ = sigm(gA[j]);
                float f_ = sigm(gA[300 + j]);
                float o_ = sigm(gA[900 + j]);
                float cn = f_ * cAr + i_ * tanh_fast(gA[600 + j]);
                float hn = o_ * tanh_fast(cn);
                if (tf < LA) cAr = cn; else hn = hA[j];
                hA[j] = hn;
            }
            {
                float i_ = sigm(gB[j]);
                float f_ = sigm(gB[300 + j]);
                float o_ = sigm(gB[900 + j]);
                float cn = f_ * cBr + i_ * tanh_fast(gB[600 + j]);
                float hn = o_ * tanh_fast(cn);
                if (tf < LB) cBr = cn; else hn = hB[j];
                hB[j] = hn;
            }
        }
        __syncthreads();
    }

    // final projection + tail fill
    if (tid >= 320) {
        float acc = dir ? 0.f : bfc[col];
        for (int j = 0; j < HID; j += 4) {
            f32x4 h4 = *(const f32x4*)&hs[j];
            acc = fmaf(h4.x, W2s[j + 0][col], acc);
            acc = fmaf(h4.y, W2s[j + 1][col], acc);
            acc = fmaf(h4.z, W2s[j + 2][col], acc);
            acc = fmaf(h4.w, W2s[j + 3][col], acc);
        }
        if (dir == 0) {
            // fwd: rows [maxL-1, 512) all carry the final/frozen h projection
            for (int t = maxL - 1; t < TT; ++t)
                __builtin_nontemporal_store(acc,
                    dst + ((size_t)bprj * TT + t) * TAGS + col);
        } else {
            // bwd: final scan step is t=0; tail rows are exactly 0
            __builtin_nontemporal_store(acc,
                dst + ((size_t)bprj * TT + 0) * TAGS + col);
            for (int t = maxL; t < TT; ++t)
                __builtin_nontemporal_store(0.f,
                    dst + ((size_t)bprj * TT + t) * TAGS + col);
        }
    }
}

// ---------------- K3: out += bwd partial ------------------------------------
__global__ __launch_bounds__(256)
void k3_add(float* __restrict__ out, const float* __restrict__ bwdp)
{
    const size_t i = ((size_t)blockIdx.x * 256 + threadIdx.x) * 4;
    f32x4 o = *(const f32x4*)(out + i);
    f32x4 bx = *(const f32x4*)(bwdp + i);
    o += bx;
    *(f32x4*)(out + i) = o;
}

extern "C" void kernel_launch(void* const* d_in, const int* in_sizes, int n_in,
                              void* d_out, int out_size, void* d_ws, size_t ws_size,
                              hipStream_t stream)
{
    const int*   tokens = (const int*)d_in[0];
    const int*   seqlen = (const int*)d_in[1];
    const float* emb    = (const float*)d_in[2];
    const float* Wf     = (const float*)d_in[3];
    const float* Uf     = (const float*)d_in[4];
    const float* bf     = (const float*)d_in[5];
    const float* Wb     = (const float*)d_in[6];
    const float* Ub     = (const float*)d_in[7];
    const float* bb     = (const float*)d_in[8];
    const float* Wfc    = (const float*)d_in[9];
    const float* bfc    = (const float*)d_in[10];
    float* out = (float*)d_out;

    // ws layout: xgf bf16 [M*G4] | xgb bf16 [M*G4] | bwdp f32 [M*64]
    const size_t xg_elems = (size_t)MM * G4;
    const size_t need = xg_elems * 2 * sizeof(unsigned short)
                      + (size_t)MM * TAGS * sizeof(float);
    if (ws_size < need) {
        // diagnostic fallback: no crash, validation will fail with out==0
        hipMemsetAsync(d_out, 0, (size_t)out_size * sizeof(float), stream);
        return;
    }
    unsigned short* xgf = (unsigned short*)d_ws;
    unsigned short* xgb = xgf + xg_elems;
    float* bwdp = (float*)(xgb + xg_elems);

    dim3 g1(MM / 64, (G4 + 63) / 64, 2);
    hipLaunchKernelGGL(k1_xg, g1, dim3(256), 0, stream,
                       tokens, seqlen, emb, Wf, bf, Wb, bb, xgf, xgb);
    hipLaunchKernelGGL(k2_rnn, dim3(64), dim3(448), 0, stream,
                       seqlen, Uf, Ub, xgf, xgb, Wfc, bfc, out, bwdp);
    hipLaunchKernelGGL(k3_add, dim3(MM * TAGS / (256 * 4)), dim3(256), 0, stream,
                       out, bwdp);
}